// Round 4
// baseline (8538.366 us; speedup 1.0000x reference)
//
#include <hip/hip_runtime.h>
#include <hip/hip_bf16.h>
#include <math.h>

// Problem constants
#define BB 2
#define NN 1024
#define HID 2048
#define NH 16
#define KVH 4
#define DD 128
#define L_TOTAL 32768
#define TOK 2048
#define NCHUNK 512

typedef __bf16 bf16;
typedef __bf16 bf16x8 __attribute__((ext_vector_type(8)));
typedef __bf16 bf16x4 __attribute__((ext_vector_type(4)));
typedef float f32x4 __attribute__((ext_vector_type(4)));

// ---------------------------------------------------------------------------
// LDS layout for seq_scan_k (byte offsets into dynamic smem; all 16B-aligned)
// K rows padded to 136 bf16 (272 B), A rows 72 bf16 (144 B), AT rows 68 f32
// (272 B), ST rows 136 bf16, xb rows 18 f32, uT rows 72 bf16 — all chosen so
// wave accesses land <=2-way per bank (2-way is free, m136).
// ---------------------------------------------------------------------------
#define KHI 0          // [2][64][136] bf16  (17408 B per buffer)
#define KLO 34816      // [2][64][136] bf16
#define AHI 69632      // [2][64][72]  bf16  (9216 B per buffer)
#define ATB 88064      // [2][64][68]  f32   (17408 B per buffer)
#define STH 122880     // [16][136] bf16
#define STL 127232     // [16][136] bf16
#define XB  131584     // [64][18] f32
#define UTH 136192     // [16][72] bf16
#define UTL 138496     // [16][72] bf16
#define DSIZE 140800

// ---------------------------------------------------------------------------
// Generic MFMA GEMM:  C[m,n] = sum_k A[m,k] * BT[n,k]   (R1-verified)
// ---------------------------------------------------------------------------
template<bool SPLIT, bool OUTBF>
__global__ __launch_bounds__(256)
void gemm_bt(const bf16* __restrict__ A, const bf16* __restrict__ Alo,
             const bf16* __restrict__ B, const bf16* __restrict__ Blo,
             float* __restrict__ Cf, bf16* __restrict__ Cb,
             int M, int N, int K, int lda, int ldb, int ldc,
             long aSb, long aSh, long aSz, long bSb, long bSh, long cSz,
             int zH, int gShift, int z0)
{
    const int zc   = blockIdx.z;
    const int z    = zc + z0;
    const int b    = z / zH;
    const int h    = z % zH;
    const int lane = threadIdx.x & 63;
    const int wave = threadIdx.x >> 6;
    const int tiles_n = N >> 4;
    const int tile = blockIdx.x * 4 + wave;
    const int mt   = tile / tiles_n;
    const int nt   = tile % tiles_n;

    const long aoff = (long)b * aSb + (long)h * aSh + (long)zc * aSz;
    const long boff = (long)b * bSb + (long)(h >> gShift) * bSh;

    const bf16* ap = A + aoff + (long)(mt * 16 + (lane & 15)) * lda + ((lane >> 4) << 3);
    const bf16* bp = B + boff + (long)(nt * 16 + (lane & 15)) * ldb + ((lane >> 4) << 3);

    f32x4 acc = {0.f, 0.f, 0.f, 0.f};
    if (!SPLIT) {
        for (int k0 = 0; k0 < K; k0 += 32) {
            bf16x8 av = *(const bf16x8*)ap;
            bf16x8 bv = *(const bf16x8*)bp;
            acc = __builtin_amdgcn_mfma_f32_16x16x32_bf16(av, bv, acc, 0, 0, 0);
            ap += 32; bp += 32;
        }
    } else {
        const bf16* apl = Alo + (ap - A);
        const bf16* bpl = Blo + (bp - B);
        for (int k0 = 0; k0 < K; k0 += 32) {
            bf16x8 av = *(const bf16x8*)ap;
            bf16x8 bv = *(const bf16x8*)bp;
            bf16x8 al = *(const bf16x8*)apl;
            bf16x8 bl = *(const bf16x8*)bpl;
            acc = __builtin_amdgcn_mfma_f32_16x16x32_bf16(av, bv, acc, 0, 0, 0);
            acc = __builtin_amdgcn_mfma_f32_16x16x32_bf16(al, bv, acc, 0, 0, 0);
            acc = __builtin_amdgcn_mfma_f32_16x16x32_bf16(av, bl, acc, 0, 0, 0);
            ap += 32; bp += 32; apl += 32; bpl += 32;
        }
    }

    const long cbase = (long)zc * cSz + (long)(nt * 16 + (lane & 15));
    const int  r0    = mt * 16 + ((lane >> 4) << 2);
    #pragma unroll
    for (int r = 0; r < 4; ++r) {
        long idx = cbase + (long)(r0 + r) * ldc;
        if (OUTBF) Cb[idx] = (bf16)acc[r];
        else       Cf[idx] = acc[r];
    }
}

// ---------------------------------------------------------------------------
// Elementwise helpers
// ---------------------------------------------------------------------------
__global__ void cast_split_k(const float* __restrict__ in, bf16* __restrict__ hi,
                             bf16* __restrict__ lo, long n)
{
    long i = (long)blockIdx.x * blockDim.x + threadIdx.x;
    if (i < n) {
        float x = in[i];
        bf16 h = (bf16)x;
        hi[i] = h;
        lo[i] = (bf16)(x - (float)h);
    }
}

__global__ void cast_k(const float* __restrict__ in, bf16* __restrict__ out, long n)
{
    long i = (long)blockIdx.x * blockDim.x + threadIdx.x;
    if (i < n) out[i] = (bf16)in[i];
}

__global__ void transpose_split_k(const float* __restrict__ in, bf16* __restrict__ hi,
                                  bf16* __restrict__ lo, int K, int N)
{
    long i = (long)blockIdx.x * blockDim.x + threadIdx.x;
    if (i < (long)K * N) {
        int n = (int)(i / K);
        int k = (int)(i % K);
        float x = in[(long)k * N + n];
        bf16 h = (bf16)x;
        hi[i] = h;
        lo[i] = (bf16)(x - (float)h);
    }
}

__global__ void vtrans_k(const float* __restrict__ v, bf16* __restrict__ vT)
{
    long i = (long)blockIdx.x * blockDim.x + threadIdx.x;
    if (i < 1048576) {
        int m   = (int)(i & 1023);
        int d   = (int)((i >> 10) & 127);
        int kvh = (int)((i >> 17) & 3);
        int b   = (int)(i >> 19);
        vT[i] = (bf16)v[((long)(b * 1024 + m)) * 512 + kvh * 128 + d];
    }
}

__global__ void softmax128_k(const float* __restrict__ in, float* __restrict__ out)
{
    const int row  = blockIdx.x;
    const int lane = threadIdx.x;
    float2 v = ((const float2*)(in + (long)row * 128))[lane];
    float m = fmaxf(v.x, v.y);
    #pragma unroll
    for (int s = 1; s < 64; s <<= 1) m = fmaxf(m, __shfl_xor(m, s, 64));
    float ex = expf(v.x - m), ey = expf(v.y - m);
    float sum = ex + ey;
    #pragma unroll
    for (int s = 1; s < 64; s <<= 1) sum += __shfl_xor(sum, s, 64);
    float inv = 1.0f / sum;
    ((float2*)(out + (long)row * 128))[lane] = make_float2(ex * inv, ey * inv);
}

__global__ void logsig_k(const float* __restrict__ in, float* __restrict__ out, long n)
{
    long i = (long)blockIdx.x * blockDim.x + threadIdx.x;
    if (i < n) {
        float x = in[i];
        float l = log1pf(expf(-fabsf(x)));
        out[i] = (fminf(x, 0.f) - l) * 0.0625f;
    }
}

__global__ void softmax_causal_k(bf16* __restrict__ P)
{
    const int row  = blockIdx.x;
    const int qi   = row & 1023;
    const int lane = threadIdx.x;
    bf16* p = P + (long)row * 1024;
    const float scale = 0.08838834764831845f;  // 1/sqrt(128)
    float vals[16];
    float m = -3.0e38f;
    #pragma unroll
    for (int t = 0; t < 16; ++t) {
        int j = lane + t * 64;
        float x = (j <= qi) ? (float)p[j] * scale : -3.0e38f;
        vals[t] = x;
        m = fmaxf(m, x);
    }
    #pragma unroll
    for (int s = 1; s < 64; s <<= 1) m = fmaxf(m, __shfl_xor(m, s, 64));
    float sum = 0.f;
    #pragma unroll
    for (int t = 0; t < 16; ++t) {
        float e = (vals[t] > -1.0e38f) ? expf(vals[t] - m) : 0.f;
        vals[t] = e;
        sum += e;
    }
    #pragma unroll
    for (int s = 1; s < 64; s <<= 1) sum += __shfl_xor(sum, s, 64);
    float inv = 1.f / sum;
    #pragma unroll
    for (int t = 0; t < 16; ++t) {
        int j = lane + t * 64;
        p[j] = (bf16)(vals[t] * inv);
    }
}

// ---------------------------------------------------------------------------
// Scan precompute kernels
// ---------------------------------------------------------------------------
// A = tril_strict(K Kt) per kv-chunk (128). Abhi [a][t][s] bf16 (MFMA B-op);
// ATf [a][s][t] f32 (substitution rows). Masked entries explicit zeros.
__global__ void prepA_k(const float* __restrict__ KLb, bf16* __restrict__ Abhi,
                        float* __restrict__ ATf)
{
    int a = blockIdx.x;
    int b = a >> 6, kvh = (a >> 4) & 3, nc = a & 15;
    const long rbase = ((long)(b * 1024 + nc * 64)) * 512 + kvh * 128;
    for (int e = threadIdx.x; e < 4096; e += 256) {
        int t = e >> 6, s = e & 63;
        float dot = 0.f;
        if (s < t) {
            const float* rt = KLb + rbase + (long)t * 512;
            const float* rs = KLb + rbase + (long)s * 512;
            for (int d = 0; d < 128; ++d) dot += rt[d] * rs[d];
        }
        Abhi[(long)a * 4096 + t * 64 + s] = (bf16)dot;
        ATf[(long)a * 4096 + s * 64 + t] = dot;
    }
}

// Aq = tril_inclusive(Q Kt) per chunk (512), split hi/lo bf16, [c][t][s].
__global__ void prepAq_k(const float* __restrict__ QLb, const float* __restrict__ KLb,
                         bf16* __restrict__ Aqhi, bf16* __restrict__ Aqlo)
{
    int c = blockIdx.x;
    int b = c >> 8, h = (c >> 4) & 15, nc = c & 15, kvh = h >> 2;
    const long qb = ((long)(b * 1024 + nc * 64)) * 2048 + h * 128;
    const long kb = ((long)(b * 1024 + nc * 64)) * 512 + kvh * 128;
    for (int e = threadIdx.x; e < 4096; e += 256) {
        int t = e >> 6, s = e & 63;
        float dot = 0.f;
        if (s <= t) {
            const float* rq = QLb + qb + (long)t * 2048;
            const float* rk = KLb + kb + (long)s * 512;
            for (int d = 0; d < 128; ++d) dot += rq[d] * rk[d];
        }
        bf16 hh = (bf16)dot;
        Aqhi[(long)c * 4096 + t * 64 + s] = hh;
        Aqlo[(long)c * 4096 + t * 64 + s] = (bf16)(dot - (float)hh);
    }
}

// ---------------------------------------------------------------------------
// global_load_lds helper: 16 B per active lane, dest = uniform base + lane*16
// ---------------------------------------------------------------------------
typedef __attribute__((address_space(1))) const unsigned int* gp_t;
typedef __attribute__((address_space(3))) unsigned int* lp_t;
__device__ __forceinline__ void gll16(const void* g, void* l)
{
    __builtin_amdgcn_global_load_lds((gp_t)g, (lp_t)l, 16, 0, 0);
}

// Stage one row of next-chunk data into LDS buffer p. idx in [0,256):
//   [0,64)   K-hi row t (256 B, 16 lanes)
//   [64,128) K-lo row t
//   [128,192) A-hi row t (128 B, 8 lanes)
//   [192,256) AT row s (256 B, 16 lanes)
__device__ __forceinline__ void stage_idx(char* sm, int p, int idx, int lane,
    const bf16* KLhi, const bf16* KLlo, const bf16* Abhi, const float* ATf,
    long krow0, long abase)
{
    if (idx < 128) {
        int t = idx & 63;
        const bf16* src = (idx < 64 ? KLhi : KLlo) + krow0 + (long)t * 512;
        char* dst = sm + (idx < 64 ? KHI : KLO) + p * 17408 + t * 272;
        if (lane < 16) gll16((const char*)src + lane * 16, dst);
    } else if (idx < 192) {
        int t = idx - 128;
        const bf16* src = Abhi + abase + (long)t * 64;
        char* dst = sm + AHI + p * 9216 + t * 144;
        if (lane < 8) gll16((const char*)src + lane * 16, dst);
    } else {
        int s = idx - 192;
        const float* src = ATf + abase + (long)s * 64;
        char* dst = sm + ATB + p * 17408 + s * 272;
        if (lane < 16) gll16((const char*)src + lane * 16, dst);
    }
}

// ---------------------------------------------------------------------------
// Sequential chunked delta-rule scan, wave-specialized.
// grid = 8 blocks x 256 threads (4 waves). Block owns value-cols [16b,16b+16).
// Wave w holds S rows [32w,32w+32) in accumulators (2 frags).
// Per chunk: [P1: all waves W=K*S0 -> xb; KT frag reads] [P2: wave0 =
// substitution chain; waves1-3 = global_load_lds prefetch of chunk c+1]
// [P3: S += Kt*u (all waves); uT/S0T -> global; S -> ST split].
// ---------------------------------------------------------------------------
__global__ __launch_bounds__(256, 1)
void seq_scan_k(const bf16* __restrict__ KLhi, const bf16* __restrict__ KLlo,
                const bf16* __restrict__ Abhi, const float* __restrict__ ATf,
                const float* __restrict__ vf, const float* __restrict__ GLb,
                bf16* __restrict__ S0Thi, bf16* __restrict__ S0Tlo,
                bf16* __restrict__ uTghi, bf16* __restrict__ uTglo)
{
    extern __shared__ char sm[];
    const int tid  = threadIdx.x;
    const int wv   = tid >> 6;
    const int lane = tid & 63;
    const int jloc = lane & 15;
    const int kq   = lane >> 4;
    const int jglob = blockIdx.x * 16 + jloc;

    // zero state LDS (incl. padding) and S0T[0] global slice
    for (int i = tid; i < 16 * 136; i += 256) {
        *(bf16*)(sm + STH + i * 2) = (bf16)0.f;
        *(bf16*)(sm + STL + i * 2) = (bf16)0.f;
    }
    for (int i = tid; i < 2048; i += 256) {
        long o = (long)(blockIdx.x * 16 + (i >> 7)) * 128 + (i & 127);
        S0Thi[o] = (bf16)0.f;
        S0Tlo[o] = (bf16)0.f;
    }

    // stage chunk 0 into buffer 0 (all waves)
    for (int idx = wv; idx < 256; idx += 4)
        stage_idx(sm, 0, idx, lane, KLhi, KLlo, Abhi, ATf, 0L, 0L);

    // wave 0: V/G prefetch for chunk 0, sub-block 0 (chunk 0: b=h=0, n0=0)
    float Vn[16], Bn[16];
    if (wv == 0) {
        #pragma unroll
        for (int s = 0; s < 16; ++s) {
            Vn[s] = vf[(long)s * 512 + jglob];
            Bn[s] = GLb[(long)s * 512 + jglob];
        }
    }
    __syncthreads();

    f32x4 S[2];
    S[0] = (f32x4){0.f, 0.f, 0.f, 0.f};
    S[1] = (f32x4){0.f, 0.f, 0.f, 0.f};

    for (int c = 0; c < NCHUNK; ++c) {
        const int p = c & 1;

        // ---- Phase 1: W = K * S0 (wave w does token rows [16w,16w+16)) ----
        f32x4 W = {0.f, 0.f, 0.f, 0.f};
        #pragma unroll
        for (int ki = 0; ki < 4; ++ki) {
            bf16x8 sh = *(const bf16x8*)(sm + STH + jloc * 272 + ki * 64 + kq * 16);
            bf16x8 sl = *(const bf16x8*)(sm + STL + jloc * 272 + ki * 64 + kq * 16);
            bf16x8 kh = *(const bf16x8*)(sm + KHI + p * 17408 + (wv * 16 + jloc) * 272 + ki * 64 + kq * 16);
            bf16x8 kl = *(const bf16x8*)(sm + KLO + p * 17408 + (wv * 16 + jloc) * 272 + ki * 64 + kq * 16);
            W = __builtin_amdgcn_mfma_f32_16x16x32_bf16(kh, sh, W, 0, 0, 0);
            W = __builtin_amdgcn_mfma_f32_16x16x32_bf16(kl, sh, W, 0, 0, 0);
            W = __builtin_amdgcn_mfma_f32_16x16x32_bf16(kh, sl, W, 0, 0, 0);
        }
        #pragma unroll
        for (int r = 0; r < 4; ++r)
            *(float*)(sm + XB + ((wv * 16 + kq * 4 + r) * 18 + jloc) * 4) = W[r];

        // KT fragments for phase 3 (this wave's S rows), strided from K LDS
        bf16x8 kth[4], ktl[4];
        #pragma unroll
        for (int mm = 0; mm < 2; ++mm) {
            const int d = (2 * wv + mm) * 16 + jloc;
            #pragma unroll
            for (int ki = 0; ki < 2; ++ki) {
                bf16x8 vh, vl;
                #pragma unroll
                for (int j = 0; j < 8; ++j) {
                    int tok = ki * 32 + kq * 8 + j;
                    vh[j] = *(const bf16*)(sm + KHI + p * 17408 + tok * 272 + d * 2);
                    vl[j] = *(const bf16*)(sm + KLO + p * 17408 + tok * 272 + d * 2);
                }
                kth[mm * 2 + ki] = vh;
                ktl[mm * 2 + ki] = vl;
            }
        }
        __syncthreads();  // B1: xb complete

        // ---- Phase 2 ----
        if (wv == 0) {
            // zero uT cols 16..63 (corr k-padding reads them as zeros)
            if (lane < 16) {
                uint4 z = {0u, 0u, 0u, 0u};
                #pragma unroll
                for (int g = 0; g < 6; ++g) {
                    *(uint4*)(sm + UTH + jloc * 144 + 32 + g * 16) = z;
                    *(uint4*)(sm + UTL + jloc * 144 + 32 + g * 16) = z;
                }
            }
            #pragma unroll
            for (int i = 0; i < 4; ++i) {
                const int T0 = i * 16;
                float Vv[16], Bv[16];
                #pragma unroll
                for (int s = 0; s < 16; ++s) { Vv[s] = Vn[s]; Bv[s] = Bn[s]; }
                // issue next sub-block's V/G (1-SB-ahead pipeline)
                {
                    int cn = c, in = i + 1;
                    if (in == 4) { in = 0; if (c + 1 < NCHUNK) cn = c + 1; }
                    int bx = cn >> 8, hx = (cn >> 4) & 15;
                    long basex = ((long)(bx * 1024 + (cn & 15) * 64 + in * 16)) * 512
                               + (hx >> 2) * 128 + jglob;
                    #pragma unroll
                    for (int s = 0; s < 16; ++s) {
                        Vn[s] = vf[basex + (long)s * 512];
                        Bn[s] = GLb[basex + (long)s * 512];
                    }
                }
                if (i > 0) {
                    // cross-SB correction: corr[j][t] = sum_{s<16i} u[j][s]*A[t][s]
                    const int K32 = (i + 1) >> 1;   // 1,1,2
                    f32x4 corr = {0.f, 0.f, 0.f, 0.f};
                    for (int ki = 0; ki < K32; ++ki) {
                        bf16x8 uh = *(const bf16x8*)(sm + UTH + jloc * 144 + ki * 64 + kq * 16);
                        bf16x8 ul = *(const bf16x8*)(sm + UTL + jloc * 144 + ki * 64 + kq * 16);
                        bf16x8 ah = *(const bf16x8*)(sm + AHI + p * 9216 + (T0 + jloc) * 144 + ki * 64 + kq * 16);
                        corr = __builtin_amdgcn_mfma_f32_16x16x32_bf16(uh, ah, corr, 0, 0, 0);
                        corr = __builtin_amdgcn_mfma_f32_16x16x32_bf16(ul, ah, corr, 0, 0, 0);
                    }
                    // D: col=lane&15 -> t=T0+jloc ; rows j = kq*4+r. RMW into xb.
                    #pragma unroll
                    for (int r = 0; r < 4; ++r)
                        *(float*)(sm + XB + ((T0 + jloc) * 18 + kq * 4 + r) * 4) += corr[r];
                }
                // xv preload (off-chain LDS reads)
                float xv[16];
                #pragma unroll
                for (int s = 0; s < 16; ++s)
                    xv[s] = *(const float*)(sm + XB + ((T0 + s) * 18 + jloc) * 4);
                // AT row prefetch ring (depth 4) from LDS, wave-uniform rows
                float rb[4][16];
                #pragma unroll
                for (int p0 = 0; p0 < 4; ++p0) {
                    const char* rp = sm + ATB + p * 17408 + (T0 + p0) * 272 + T0 * 4;
                    #pragma unroll
                    for (int g = 0; g < 4; ++g) {
                        float4 v4 = *(const float4*)(rp + g * 16);
                        rb[p0][4 * g] = v4.x; rb[p0][4 * g + 1] = v4.y;
                        rb[p0][4 * g + 2] = v4.z; rb[p0][4 * g + 3] = v4.w;
                    }
                }
                float acc[16];
                #pragma unroll
                for (int t = 0; t < 16; ++t) acc[t] = 0.f;

                #pragma unroll
                for (int s = 0; s < 16; ++s) {
                    float u = Bv[s] * (Vv[s] - xv[s] - acc[s]);
                    bf16 uh16 = (bf16)u;
                    bf16 ul16 = (bf16)(u - (float)uh16);
                    if (lane < 16) {
                        *(bf16*)(sm + UTH + jloc * 144 + (T0 + s) * 2) = uh16;
                        *(bf16*)(sm + UTL + jloc * 144 + (T0 + s) * 2) = ul16;
                    }
                    #pragma unroll
                    for (int t = 0; t < 16; ++t)
                        if (t > s) acc[t] += rb[s & 3][t] * u;
                    int rr = T0 + s + 4; if (rr > 63) rr = 63;
                    const char* rp = sm + ATB + p * 17408 + rr * 272 + T0 * 4;
                    #pragma unroll
                    for (int g = 0; g < 4; ++g) {
                        float4 v4 = *(const float4*)(rp + g * 16);
                        rb[s & 3][4 * g] = v4.x; rb[s & 3][4 * g + 1] = v4.y;
                        rb[s & 3][4 * g + 2] = v4.z; rb[s & 3][4 * g + 3] = v4.w;
                    }
                }
            }
        } else {
            // waves 1-3: prefetch chunk c+1 into the other buffers
            if (c + 1 < NCHUNK) {
                const int cn = c + 1;
                const int bn = cn >> 8, hn = (cn >> 4) & 15, ncn = cn & 15;
                const int kvn = hn >> 2;
                const long krow0n = ((long)(bn * 1024 + ncn * 64)) * 512 + kvn * 128;
                const long abasen = (long)((bn * 4 + kvn) * 16 + ncn) * 4096;
                const int pn = p ^ 1;
                for (int idx = wv - 1; idx < 256; idx += 3)
                    stage_idx(sm, pn, idx, lane, KLhi, KLlo, Abhi, ATf, krow0n, abasen);
            }
        }
        __syncthreads();  // B2: uT complete; prefetch loads drained

        // ---- Phase 3: S += Kt * u (wave w updates its 2 row-blocks) ----
        #pragma unroll
        for (int ki = 0; ki < 2; ++ki) {
            bf16x8 uh = *(const bf16x8*)(sm + UTH + jloc * 144 + ki * 64 + kq * 16);
            bf16x8 ul = *(const bf16x8*)(sm + UTL + jloc * 144 + ki * 64 + kq * 16);
            #pragma unroll
            for (int mm = 0; mm < 2; ++mm) {
                S[mm] = __builtin_amdgcn_mfma_f32_16x16x32_bf16(kth[mm * 2 + ki], uh, S[mm], 0, 0, 0);
                S[mm] = __builtin_amdgcn_mfma_f32_16x16x32_bf16(kth[mm * 2 + ki], ul, S[mm], 0, 0, 0);
                S[mm] = __builtin_amdgcn_mfma_f32_16x16x32_bf16(ktl[mm * 2 + ki], uh, S[mm], 0, 0, 0);
            }
        }

        // uT -> global (waves 1 and 2, for pass 2)
        if (wv == 1 || wv == 2) {
            const int off = (wv == 1) ? UTH : UTL;
            bf16* dst = (wv == 1) ? uTghi : uTglo;
            const int row = lane >> 2, colb = (lane & 3) * 16;
            char* db = (char*)(dst + ((long)c * 128 + blockIdx.x * 16 + row) * 64);
            #pragma unroll
            for (int hh = 0; hh < 2; ++hh) {
                uint4 v = *(const uint4*)(sm + off + row * 144 + hh * 64 + colb);
                *(uint4*)(db + hh * 64 + colb) = v;
            }
        }

        // epilogue: split S -> ST (next chunk) + S0T[c+1] (global, pass 2)
        #pragma unroll
        for (int mm = 0; mm < 2; ++mm) {
            const int m = 2 * wv + mm;
            bf16x4 h4, l4;
            #pragma unroll
            for (int r = 0; r < 4; ++r) {
                float v = S[mm][r];
                bf16 hh2 = (bf16)v;
                h4[r] = hh2;
                l4[r] = (bf16)(v - (float)hh2);
            }
            const int d0 = m * 16 + kq * 4;
            *(bf16x4*)(sm + STH + jloc * 272 + d0 * 2) = h4;
            *(bf16x4*)(sm + STL + jloc * 272 + d0 * 2) = l4;
            long goff = (long)(c + 1) * 16384 + (long)jglob * 128 + d0;
            *(bf16x4*)(S0Thi + goff) = h4;
            *(bf16x4*)(S0Tlo + goff) = l4;
        }
        __syncthreads();  // B3: ST/uT stable for next chunk
    }
}

// ---------------------------------------------------------------------------
// Pass 2 (fully parallel): o[t][j] = Q*S0_c + tril_incl(Aq)*u  per chunk.
// ---------------------------------------------------------------------------
__global__ __launch_bounds__(256)
void pass2_o_k(const bf16* __restrict__ QLhi, const bf16* __restrict__ QLlo,
               const bf16* __restrict__ S0Thi, const bf16* __restrict__ S0Tlo,
               const bf16* __restrict__ Aqhi, const bf16* __restrict__ Aqlo,
               const bf16* __restrict__ uTghi, const bf16* __restrict__ uTglo,
               float* __restrict__ O)
{
    const int c    = blockIdx.x >> 3;
    const int tg   = blockIdx.x & 7;
    const int wave = threadIdx.x >> 6;
    const int lane = threadIdx.x & 63;
    const int tt   = tg * 4 + wave;
    const int mt   = tt >> 3, nt = tt & 7;
    const int b = c >> 8, h = (c >> 4) & 15, nc = c & 15, n0 = nc * 64;
    const int kq = lane >> 4, l15 = lane & 15;

    const long qrow   = ((long)(b * 1024 + n0 + mt * 16 + l15)) * 2048 + h * 128;
    const long sbase  = (long)c * 16384 + (long)(nt * 16 + l15) * 128;
    const long aqbase = (long)c * 4096 + (long)(mt * 16 + l15) * 64;
    const long ubase  = ((long)(c * 128 + nt * 16 + l15)) * 64;

    f32x4 acc = {0.f, 0.f, 0.f, 0.f};
    #pragma unroll
    for (int ki = 0; ki < 4; ++ki) {
        bf16x8 qh = *(const bf16x8*)(QLhi + qrow + ki * 32 + kq * 8);
        bf16x8 ql = *(const bf16x8*)(QLlo + qrow + ki * 32 + kq * 8);
        bf16x8 sh = *(const bf16x8*)(S0Thi + sbase + ki * 32 + kq * 8);
        bf16x8 sl = *(const bf16x8*)(S0Tlo + sbase + ki * 32 + kq * 8);
        acc = __builtin_amdgcn_mfma_f32_16x16x32_bf16(qh, sh, acc, 0, 0, 0);
        acc = __builtin_amdgcn_mfma_f32_16x16x32_bf16(ql, sh, acc, 0, 0, 0);
        acc = __builtin_amdgcn_mfma_f32_16x16x32_bf16(qh, sl, acc, 0, 0, 0);
    }
    #pragma unroll
    for (int ki = 0; ki < 2; ++ki) {
        bf16x8 ah = *(const bf16x8*)(Aqhi + aqbase + ki * 32 + kq * 8);
        bf16x8 al = *(const bf16x8*)(Aqlo + aqbase + ki * 32 + kq * 8);
        bf16x8 uh = *(const bf16x8*)(uTghi + ubase + ki * 32 + kq * 8);
        bf16x8 ul = *(const bf16x8*)(uTglo + ubase + ki * 32 + kq * 8);
        acc = __builtin_amdgcn_mfma_f32_16x16x32_bf16(ah, uh, acc, 0, 0, 0);
        acc = __builtin_amdgcn_mfma_f32_16x16x32_bf16(al, uh, acc, 0, 0, 0);
        acc = __builtin_amdgcn_mfma_f32_16x16x32_bf16(ah, ul, acc, 0, 0, 0);
    }
    #pragma unroll
    for (int r = 0; r < 4; ++r)
        O[((long)c * 64 + mt * 16 + kq * 4 + r) * 128 + nt * 16 + l15] = acc[r];
}

// oComb[(b,n),(h,d)] = 0.5*(oLin[(b,h,n),d] + oBase[(b,h,n),d])  -> bf16
__global__ void combine_k(const float* __restrict__ oLin, const bf16* __restrict__ oBase,
                          bf16* __restrict__ oComb, long n)
{
    long i = (long)blockIdx.x * blockDim.x + threadIdx.x;
    if (i < n) {
        int d  = (int)(i & 127);
        int hh = (int)((i >> 7) & 15);
        int nn = (int)((i >> 11) & 1023);
        int b  = (int)(i >> 21);
        long src = ((long)((b * 16 + hh) * 1024 + nn)) * 128 + d;
        oComb[i] = (bf16)(0.5f * (oLin[src] + (float)oBase[src]));
    }
}

// ---------------------------------------------------------------------------
extern "C" void kernel_launch(void* const* d_in, const int* in_sizes, int n_in,
                              void* d_out, int out_size, void* d_ws, size_t ws_size,
                              hipStream_t stream)
{
    const float* hs = (const float*)d_in[0];
    const float* Wq = (const float*)d_in[1];
    const float* Wk = (const float*)d_in[2];
    const float* Wv = (const float*)d_in[3];
    const float* Wo = (const float*)d_in[4];

    char* base = (char*)d_ws;
    size_t off = 0;
    auto alloc = [&](size_t bytes) -> char* {
        char* r = base + off;
        off += (bytes + 255) & ~(size_t)255;
        return r;
    };

    bf16* hsHi  = (bf16*)alloc((long)TOK * 2048 * 2);
    bf16* hsLo  = (bf16*)alloc((long)TOK * 2048 * 2);
    bf16* WqTHi = (bf16*)alloc(2048L * 2048 * 2);
    bf16* WqTLo = (bf16*)alloc(2048L * 2048 * 2);
    bf16* WkTHi = (bf16*)alloc(512L * 2048 * 2);
    bf16* WkTLo = (bf16*)alloc(512L * 2048 * 2);
    bf16* WvTHi = (bf16*)alloc(512L * 2048 * 2);
    bf16* WvTLo = (bf16*)alloc(512L * 2048 * 2);
    bf16* WoTHi = (bf16*)alloc(2048L * 2048 * 2);
    bf16* WoTLo = (bf16*)alloc(2048L * 2048 * 2);
    float* qf   = (float*)alloc((long)TOK * 2048 * 4);
    float* kf   = (float*)alloc((long)TOK * 512 * 4);
    float* vf   = (float*)alloc((long)TOK * 512 * 4);
    float* QLb  = (float*)alloc((long)TOK * 2048 * 4);
    float* KLb  = (float*)alloc((long)TOK * 512 * 4);
    float* GLb  = (float*)alloc((long)TOK * 512 * 4);
    bf16* qhB   = (bf16*)alloc((long)TOK * 2048 * 2);
    bf16* khB   = (bf16*)alloc((long)TOK * 512 * 2);
    bf16* vT    = (bf16*)alloc(1048576L * 2);
    bf16* P     = (bf16*)alloc(8L * 1024 * 1024 * 2);
    float* oLin = (float*)alloc(32768L * 128 * 4);
    bf16* oBase = (bf16*)alloc(32768L * 128 * 2);
    bf16* oComb = (bf16*)alloc((long)TOK * 2048 * 2);
    // scan machinery
    bf16* KLhi  = (bf16*)alloc((long)TOK * 512 * 2);
    bf16* KLlo  = (bf16*)alloc((long)TOK * 512 * 2);
    bf16* QLhi  = (bf16*)alloc((long)TOK * 2048 * 2);
    bf16* QLlo  = (bf16*)alloc((long)TOK * 2048 * 2);
    bf16* Abhi  = (bf16*)alloc(128L * 4096 * 2);
    float* ATf  = (float*)alloc(128L * 4096 * 4);
    bf16* Aqhi  = (bf16*)alloc(512L * 4096 * 2);
    bf16* Aqlo  = (bf16*)alloc(512L * 4096 * 2);
    bf16* S0Thi = (bf16*)alloc(513L * 16384 * 2);
    bf16* S0Tlo = (bf16*)alloc(513L * 16384 * 2);
    bf16* uTghi = (bf16*)alloc(512L * 128 * 64 * 2);
    bf16* uTglo = (bf16*)alloc(512L * 128 * 64 * 2);

    const int T256 = 256;
    // casts / transposes
    cast_split_k<<<(TOK * 2048 + 255) / 256, T256, 0, stream>>>(hs, hsHi, hsLo, (long)TOK * 2048);
    transpose_split_k<<<(2048L * 2048 + 255) / 256, T256, 0, stream>>>(Wq, WqTHi, WqTLo, 2048, 2048);
    transpose_split_k<<<(2048L * 512 + 255) / 256, T256, 0, stream>>>(Wk, WkTHi, WkTLo, 2048, 512);
    transpose_split_k<<<(2048L * 512 + 255) / 256, T256, 0, stream>>>(Wv, WvTHi, WvTLo, 2048, 512);
    transpose_split_k<<<(2048L * 2048 + 255) / 256, T256, 0, stream>>>(Wo, WoTHi, WoTLo, 2048, 2048);

    // projections (split-bf16 ~ fp32 accuracy)
    gemm_bt<true, false><<<dim3(4096, 1, 1), T256, 0, stream>>>(
        hsHi, hsLo, WqTHi, WqTLo, qf, nullptr,
        2048, 2048, 2048, 2048, 2048, 2048, 0, 0, 0, 0, 0, 0, 1, 0, 0);
    gemm_bt<true, false><<<dim3(1024, 1, 1), T256, 0, stream>>>(
        hsHi, hsLo, WkTHi, WkTLo, kf, nullptr,
        2048, 512, 2048, 2048, 2048, 512, 0, 0, 0, 0, 0, 0, 1, 0, 0);
    gemm_bt<true, false><<<dim3(1024, 1, 1), T256, 0, stream>>>(
        hsHi, hsLo, WvTHi, WvTLo, vf, nullptr,
        2048, 512, 2048, 2048, 2048, 512, 0, 0, 0, 0, 0, 0, 1, 0, 0);

    // scan-input prep
    softmax128_k<<<32768, 64, 0, stream>>>(qf, QLb);
    softmax128_k<<<8192, 64, 0, stream>>>(kf, KLb);
    logsig_k<<<(1048576 + 255) / 256, T256, 0, stream>>>(kf, GLb, 1048576);

    // attention-branch inputs
    cast_k<<<(TOK * 2048 + 255) / 256, T256, 0, stream>>>(qf, qhB, (long)TOK * 2048);
    cast_k<<<(TOK * 512 + 255) / 256, T256, 0, stream>>>(kf, khB, (long)TOK * 512);
    vtrans_k<<<(1048576 + 255) / 256, T256, 0, stream>>>(vf, vT);

    // scan precompute
    cast_split_k<<<(TOK * 512 + 255) / 256, T256, 0, stream>>>(KLb, KLhi, KLlo, (long)TOK * 512);
    cast_split_k<<<(TOK * 2048 + 255) / 256, T256, 0, stream>>>(QLb, QLhi, QLlo, (long)TOK * 2048);
    prepA_k<<<128, T256, 0, stream>>>(KLb, Abhi, ATf);
    prepAq_k<<<512, T256, 0, stream>>>(QLb, KLb, Aqhi, Aqlo);

    // attention branch, chunked over 8 (b,h) pairs to bound the P buffer
    for (int z0 = 0; z0 < 32; z0 += 8) {
        gemm_bt<false, true><<<dim3(1024, 1, 8), T256, 0, stream>>>(
            qhB, nullptr, khB, nullptr, nullptr, P,
            1024, 1024, 128, 2048, 512, 1024,
            2097152L, 128L, 0L, 524288L, 128L, 1048576L, 16, 2, z0);
        softmax_causal_k<<<8192, 64, 0, stream>>>(P);
        gemm_bt<false, true><<<dim3(128, 1, 8), T256, 0, stream>>>(
            P, nullptr, vT, nullptr, nullptr, oBase + (long)z0 * 131072,
            1024, 128, 1024, 1024, 1024, 128,
            0L, 0L, 1048576L, 524288L, 131072L, 131072L, 16, 2, z0);
    }

    // chunked delta-rule scan: sequential chain (wave-specialized) + parallel pass 2
    static bool attr_set = false;
    (void)attr_set;
    hipFuncSetAttribute((const void*)seq_scan_k,
                        hipFuncAttributeMaxDynamicSharedMemorySize, DSIZE);
    seq_scan_k<<<8, T256, DSIZE, stream>>>(KLhi, KLlo, Abhi, ATf, vf, GLb,
                                           S0Thi, S0Tlo, uTghi, uTglo);
    pass2_o_k<<<4096, T256, 0, stream>>>(QLhi, QLlo, S0Thi, S0Tlo, Aqhi, Aqlo,
                                         uTghi, uTglo, oLin);

    // combine branches and output projection
    combine_k<<<(TOK * 2048 + 255) / 256, T256, 0, stream>>>(oLin, oBase, oComb, (long)TOK * 2048);
    gemm_bt<false, false><<<dim3(4096, 1, 1), T256, 0, stream>>>(
        oComb, nullptr, WoTHi, nullptr, (float*)d_out, nullptr,
        2048, 2048, 2048, 2048, 2048, 2048, 0, 0, 0, 0, 0, 0, 1, 0, 0);
}